// Round 2
// baseline (95.857 us; speedup 1.0000x reference)
//
#include <hip/hip_runtime.h>

#define SS 4096
#define CC 128
#define BB 32
#define KW 25
#define PADW 12
#define CH 64               // rows per chunk in K1
#define NCHUNK (SS / CH)    // 64

// ---------------- K1: trend (fp32 sequential window sum, ref order) + stats --
__global__ __launch_bounds__(128)
void k1_trend_stats(const float* __restrict__ x, float* __restrict__ trend,
                    float* __restrict__ stats) {
    const int blk = blockIdx.x;
    const int b = blk / NCHUNK;
    const int chunk = blk % NCHUNK;
    const int s0 = chunk * CH;
    const int c = threadIdx.x;

    const float* xs = x + (size_t)b * SS * CC + c;
    float* ts = trend + (size_t)b * SS * CC + c;

    // win[j] = x[s0 - 12 + j], zero-padded (all static indices -> registers)
    float win[KW];
    #pragma unroll
    for (int j = 0; j < KW; ++j) {
        const int s = s0 - PADW + j;
        win[j] = (s >= 0 && s < SS) ? xs[s * CC] : 0.0f;
    }

    float Sx_e = 0.f, Sx_o = 0.f, Sx2 = 0.f;
    float Sa = 0.f, Sa2 = 0.f;
    float Sw_e = 0.f, Sw_o = 0.f, Sw2 = 0.f;

    for (int i = 0; i < CH; ++i) {
        const int s = s0 + i;
        // fp32 sequential sum in ascending window order == XLA reduce_window
        float acc = win[0];
        #pragma unroll
        for (int j = 1; j < KW; ++j) acc += win[j];
        const float tf = acc / 25.0f;   // IEEE f32 divide, matches sums / K
        ts[s * CC] = tf;

        const float xv = win[PADW];     // x[s]
        const float a = xv - tf;        // x - trend
        const float w = 0.5f * xv - tf; // resid minus parity constant
        if (s & 1) { Sx_o += xv; Sw_o += w; }
        else       { Sx_e += xv; Sw_e += w; }
        Sx2 += xv * xv;
        Sa  += a;  Sa2 += a * a;
        Sw2 += w * w;

        // shift window: drop x[s-12], append x[s+13]
        #pragma unroll
        for (int j = 0; j < KW - 1; ++j) win[j] = win[j + 1];
        const int sn = s + PADW + 1;
        win[KW - 1] = (sn < SS) ? xs[sn * CC] : 0.0f;
    }

    const int series = b * CC + c;              // 0..4095
    const int stride = BB * CC;                 // 4096
    float* st = stats + (size_t)chunk * stride + series;
    const size_t jstride = (size_t)NCHUNK * stride;
    st[0 * jstride] = Sx_e;
    st[1 * jstride] = Sx_o;
    st[2 * jstride] = Sx2;
    st[3 * jstride] = Sa;
    st[4 * jstride] = Sa2;
    st[5 * jstride] = Sw_e;
    st[6 * jstride] = Sw_o;
    st[7 * jstride] = Sw2;
}

// ---------------- K2: reduce chunk partials -> cond per series ---------------
__global__ __launch_bounds__(256)
void k2_finalize(const float* __restrict__ stats, float* __restrict__ condf) {
    const int series = blockIdx.x * 256 + threadIdx.x;  // 0..4095
    const int stride = BB * CC;
    const size_t jstride = (size_t)NCHUNK * stride;

    float acc[8];
    #pragma unroll
    for (int j = 0; j < 8; ++j) acc[j] = 0.f;
    for (int k = 0; k < NCHUNK; ++k) {
        #pragma unroll
        for (int j = 0; j < 8; ++j)
            acc[j] += stats[j * jstride + (size_t)k * stride + series];
    }
    const float Sx_e = acc[0], Sx_o = acc[1], Sx2 = acc[2];
    const float Sa = acc[3], Sa2 = acc[4];
    const float Sw_e = acc[5], Sw_o = acc[6], Sw2 = acc[7];

    const float Sf = (float)SS;
    const float c_e = Sx_o / Sf;   // opposite-parity mean at even n
    const float c_o = Sx_e / Sf;   // at odd n
    const float halfS = 0.5f * Sf;
    const float sum_c = halfS * (c_e + c_o);
    const float sumsq_c = halfS * (c_e * c_e + c_o * c_o);

    // v1 = resid = w + c_p
    const float s1 = (Sw_e + Sw_o) + sum_c;
    const float q1 = Sw2 + 2.f * (c_e * Sw_e + c_o * Sw_o) + sumsq_c;
    const float var1 = (q1 - s1 * s1 / Sf) / (Sf - 1.f);
    // v2 = trend + resid = 0.5x + c_p
    const float s2 = 0.5f * (Sx_e + Sx_o) + sum_c;
    const float q2 = 0.25f * Sx2 + (c_e * Sx_e + c_o * Sx_o) + sumsq_c;
    const float var2 = (q2 - s2 * s2 / Sf) / (Sf - 1.f);
    // v3 = seasonal0 + resid = x - trend = a
    const float var3 = (Sa2 - Sa * Sa / Sf) / (Sf - 1.f);

    const float d_t = 1.f - var1 / (var2 + 1e-8f);
    const float d_s = 1.f - var1 / (var3 + 1e-8f);
    condf[series] = (d_t > 0.5f || d_s > 0.5f) ? 1.f : 0.f;
}

// ---------------- K3: seasonal = cond ? x/(trend+eps) : x - trend ------------
__global__ __launch_bounds__(256)
void k3_seasonal(const float* __restrict__ x, const float* __restrict__ trend,
                 const float* __restrict__ condf, float* __restrict__ seasonal) {
    const int total4 = BB * SS * CC / 4;  // 4,194,304 float4s
    for (int q = blockIdx.x * blockDim.x + threadIdx.x; q < total4;
         q += gridDim.x * blockDim.x) {
        const int e = q * 4;
        const int b = e >> 19;          // / (SS*CC)
        const int c = e & (CC - 1);     // quad-aligned channel base
        const float4 x4 = *(const float4*)(x + e);
        const float4 t4 = *(const float4*)(trend + e);
        const float4 c4 = *(const float4*)(condf + b * CC + c);
        float4 o;
        o.x = (c4.x > 0.5f) ? x4.x / (t4.x + 1e-8f) : x4.x - t4.x;
        o.y = (c4.y > 0.5f) ? x4.y / (t4.y + 1e-8f) : x4.y - t4.y;
        o.z = (c4.z > 0.5f) ? x4.z / (t4.z + 1e-8f) : x4.z - t4.z;
        o.w = (c4.w > 0.5f) ? x4.w / (t4.w + 1e-8f) : x4.w - t4.w;
        *(float4*)(seasonal + e) = o;
    }
}

extern "C" void kernel_launch(void* const* d_in, const int* in_sizes, int n_in,
                              void* d_out, int out_size, void* d_ws, size_t ws_size,
                              hipStream_t stream) {
    const float* x = (const float*)d_in[0];
    float* out = (float*)d_out;
    float* trend = out;                               // output 0
    float* seasonal = out + (size_t)BB * SS * CC;     // output 1

    // stats scratch lives in the seasonal half of d_out (overwritten by K3);
    // only cond (16 KiB) uses d_ws.
    float* stats = seasonal;                          // 8*64*4096 floats = 8 MiB
    float* condf = (float*)d_ws;                      // 4096 floats

    k1_trend_stats<<<dim3(BB * NCHUNK), dim3(CC), 0, stream>>>(x, trend, stats);
    k2_finalize<<<dim3(16), dim3(256), 0, stream>>>(stats, condf);
    k3_seasonal<<<dim3(2048), dim3(256), 0, stream>>>(x, trend, condf, seasonal);
}

// Round 3
// 91.716 us; speedup vs baseline: 1.0452x; 1.0452x over previous
//
#include <hip/hip_runtime.h>

#define SS 4096
#define CC 128
#define BB 32
#define KW 25
#define PADW 12
#define CH 64               // rows per chunk in K1
#define NCHUNK (SS / CH)    // 64
#define NSERIES (BB * CC)   // 4096

// ---------------- K1: trend (fp32 sequential window sum, ref order) + stats --
__global__ __launch_bounds__(128)
void k1_trend_stats(const float* __restrict__ x, float* __restrict__ trend,
                    float* __restrict__ stats) {
    const int blk = blockIdx.x;
    const int b = blk / NCHUNK;
    const int chunk = blk % NCHUNK;
    const int s0 = chunk * CH;          // even (CH=64) -> parity of s == i&1
    const int c = threadIdx.x;

    const float* xs = x + (size_t)b * SS * CC + c;
    float* ts = trend + (size_t)b * SS * CC + c;

    // win[j] = x[s0 - 12 + j], zero-padded
    float win[KW];
    #pragma unroll
    for (int j = 0; j < KW; ++j) {
        const int s = s0 - PADW + j;
        win[j] = (s >= 0 && s < SS) ? xs[s * CC] : 0.0f;
    }

    float Sx_e = 0.f, Sx_o = 0.f, Sx2 = 0.f;
    float Sa = 0.f, Sa2 = 0.f;
    float Sw_e = 0.f, Sw_o = 0.f, Sw2 = 0.f;

    // Full unroll: register renaming replaces the 24-mov window shift,
    // and the parity branch becomes compile-time (i&1).
    #pragma unroll
    for (int i = 0; i < CH; ++i) {
        const int s = s0 + i;
        // fp32 sequential sum in ascending window order == XLA reduce_window
        float acc = win[0];
        #pragma unroll
        for (int j = 1; j < KW; ++j) acc += win[j];
        const float tf = acc / 25.0f;   // IEEE f32 divide, matches sums / K
        ts[s * CC] = tf;

        const float xv = win[PADW];     // x[s]
        const float a = xv - tf;        // x - trend
        const float w = 0.5f * xv - tf; // resid minus parity constant
        if (i & 1) { Sx_o += xv; Sw_o += w; }
        else       { Sx_e += xv; Sw_e += w; }
        Sx2 += xv * xv;
        Sa  += a;  Sa2 += a * a;
        Sw2 += w * w;

        // shift window (renamed away by the unroll)
        #pragma unroll
        for (int j = 0; j < KW - 1; ++j) win[j] = win[j + 1];
        const int sn = s + PADW + 1;
        win[KW - 1] = (sn < SS) ? xs[sn * CC] : 0.0f;
    }

    const int series = b * CC + c;              // 0..4095
    float* st = stats + (size_t)chunk * NSERIES + series;
    const size_t jstride = (size_t)NCHUNK * NSERIES;
    st[0 * jstride] = Sx_e;
    st[1 * jstride] = Sx_o;
    st[2 * jstride] = Sx2;
    st[3 * jstride] = Sa;
    st[4 * jstride] = Sa2;
    st[5 * jstride] = Sw_e;
    st[6 * jstride] = Sw_o;
    st[7 * jstride] = Sw2;
}

// ---------------- K2: reduce chunk partials -> cond per series ---------------
// 128 blocks x 256 threads; block handles 32 series, 8 threads per series
// (one per stat j). j = tid>>5 so a wave's 32 lanes read adjacent series.
__global__ __launch_bounds__(256)
void k2_finalize(const float* __restrict__ stats, float* __restrict__ condf) {
    const int j = threadIdx.x >> 5;          // stat index 0..7
    const int sl = threadIdx.x & 31;         // series local 0..31
    const int series = blockIdx.x * 32 + sl; // 0..4095
    const size_t jstride = (size_t)NCHUNK * NSERIES;

    const float* p = stats + j * jstride + series;
    float a = 0.f;
    #pragma unroll 8
    for (int k = 0; k < NCHUNK; ++k) a += p[(size_t)k * NSERIES];

    __shared__ float red[32][9];             // +1 pad
    red[sl][j] = a;
    __syncthreads();
    if (threadIdx.x < 32) {
        const int me = threadIdx.x;
        const float Sx_e = red[me][0], Sx_o = red[me][1], Sx2 = red[me][2];
        const float Sa = red[me][3], Sa2 = red[me][4];
        const float Sw_e = red[me][5], Sw_o = red[me][6], Sw2 = red[me][7];

        const float Sf = (float)SS;
        const float c_e = Sx_o / Sf;   // opposite-parity mean at even n
        const float c_o = Sx_e / Sf;   // at odd n
        const float halfS = 0.5f * Sf;
        const float sum_c = halfS * (c_e + c_o);
        const float sumsq_c = halfS * (c_e * c_e + c_o * c_o);

        // v1 = resid = w + c_p
        const float s1 = (Sw_e + Sw_o) + sum_c;
        const float q1 = Sw2 + 2.f * (c_e * Sw_e + c_o * Sw_o) + sumsq_c;
        const float var1 = (q1 - s1 * s1 / Sf) / (Sf - 1.f);
        // v2 = trend + resid = 0.5x + c_p
        const float s2 = 0.5f * (Sx_e + Sx_o) + sum_c;
        const float q2 = 0.25f * Sx2 + (c_e * Sx_e + c_o * Sx_o) + sumsq_c;
        const float var2 = (q2 - s2 * s2 / Sf) / (Sf - 1.f);
        // v3 = seasonal0 + resid = x - trend
        const float var3 = (Sa2 - Sa * Sa / Sf) / (Sf - 1.f);

        const float d_t = 1.f - var1 / (var2 + 1e-8f);
        const float d_s = 1.f - var1 / (var3 + 1e-8f);
        condf[blockIdx.x * 32 + me] = (d_t > 0.5f || d_s > 0.5f) ? 1.f : 0.f;
    }
}

// ---------------- K3: seasonal = cond ? x/(trend+eps) : x - trend ------------
__global__ __launch_bounds__(256)
void k3_seasonal(const float* __restrict__ x, const float* __restrict__ trend,
                 const float* __restrict__ condf, float* __restrict__ seasonal) {
    const int total4 = BB * SS * CC / 4;  // 4,194,304 float4s
    for (int q = blockIdx.x * blockDim.x + threadIdx.x; q < total4;
         q += gridDim.x * blockDim.x) {
        const int e = q * 4;
        const int b = e >> 19;          // / (SS*CC)
        const int c = e & (CC - 1);     // quad-aligned channel base
        const float4 x4 = *(const float4*)(x + e);
        const float4 t4 = *(const float4*)(trend + e);
        const float4 c4 = *(const float4*)(condf + b * CC + c);
        float4 o;
        o.x = (c4.x > 0.5f) ? x4.x / (t4.x + 1e-8f) : x4.x - t4.x;
        o.y = (c4.y > 0.5f) ? x4.y / (t4.y + 1e-8f) : x4.y - t4.y;
        o.z = (c4.z > 0.5f) ? x4.z / (t4.z + 1e-8f) : x4.z - t4.z;
        o.w = (c4.w > 0.5f) ? x4.w / (t4.w + 1e-8f) : x4.w - t4.w;
        *(float4*)(seasonal + e) = o;
    }
}

extern "C" void kernel_launch(void* const* d_in, const int* in_sizes, int n_in,
                              void* d_out, int out_size, void* d_ws, size_t ws_size,
                              hipStream_t stream) {
    const float* x = (const float*)d_in[0];
    float* out = (float*)d_out;
    float* trend = out;                               // output 0
    float* seasonal = out + (size_t)BB * SS * CC;     // output 1

    // stats scratch lives in the seasonal half of d_out (overwritten by K3);
    // only cond (16 KiB) uses d_ws.
    float* stats = seasonal;                          // 8*64*4096 floats = 8 MiB
    float* condf = (float*)d_ws;                      // 4096 floats

    k1_trend_stats<<<dim3(BB * NCHUNK), dim3(CC), 0, stream>>>(x, trend, stats);
    k2_finalize<<<dim3(NSERIES / 32), dim3(256), 0, stream>>>(stats, condf);
    k3_seasonal<<<dim3(2048), dim3(256), 0, stream>>>(x, trend, condf, seasonal);
}

// Round 4
// 83.028 us; speedup vs baseline: 1.1545x; 1.1046x over previous
//
#include <hip/hip_runtime.h>

#define SS 4096
#define CC 128
#define BB 32
#define KW 25
#define PADW 12
#define CH 32               // rows per chunk in K1
#define NCHUNK (SS / CH)    // 128
#define NSERIES (BB * CC)   // 4096
#define NBLK (BB * NCHUNK)  // 4096 K1 blocks
#define NXCD 8

// ---------------- K1: trend (fp32 sequential window sum, ref order) + stats --
__global__ __launch_bounds__(128, 6)
void k1_trend_stats(const float* __restrict__ x, float* __restrict__ trend,
                    float* __restrict__ stats) {
    // XCD-contiguous swizzle: XCD k owns virtual ids [k*512, (k+1)*512)
    // = 4 whole batches -> window-halo re-reads hit the local L2.
    const int v = (blockIdx.x % NXCD) * (NBLK / NXCD) + blockIdx.x / NXCD;
    const int b = v / NCHUNK;
    const int chunk = v % NCHUNK;
    const int s0 = chunk * CH;          // even -> parity of s == i&1
    const int c = threadIdx.x;

    const float* xs = x + (size_t)b * SS * CC + c;
    float* ts = trend + (size_t)b * SS * CC + c;

    // win[j] = x[s0 - 12 + j], zero-padded
    float win[KW];
    #pragma unroll
    for (int j = 0; j < KW; ++j) {
        const int s = s0 - PADW + j;
        win[j] = (s >= 0 && s < SS) ? xs[s * CC] : 0.0f;
    }

    float Sx_e = 0.f, Sx_o = 0.f, Sx2 = 0.f;
    float Sa = 0.f, Sa2 = 0.f;
    float Sw_e = 0.f, Sw_o = 0.f, Sw2 = 0.f;

    #pragma unroll
    for (int i = 0; i < CH; ++i) {
        const int s = s0 + i;
        // fp32 sequential sum in ascending window order == XLA reduce_window
        float acc = win[0];
        #pragma unroll
        for (int j = 1; j < KW; ++j) acc += win[j];
        const float tf = acc / 25.0f;   // IEEE f32 divide, matches sums / K
        ts[s * CC] = tf;

        const float xv = win[PADW];     // x[s]
        const float a = xv - tf;        // x - trend
        const float w = 0.5f * xv - tf; // resid minus parity constant
        if (i & 1) { Sx_o += xv; Sw_o += w; }
        else       { Sx_e += xv; Sw_e += w; }
        Sx2 += xv * xv;
        Sa  += a;  Sa2 += a * a;
        Sw2 += w * w;

        // shift window (renamed away by the unroll)
        #pragma unroll
        for (int j = 0; j < KW - 1; ++j) win[j] = win[j + 1];
        const int sn = s + PADW + 1;
        win[KW - 1] = (sn < SS) ? xs[sn * CC] : 0.0f;
    }

    const int series = b * CC + c;              // 0..4095
    float* st = stats + (size_t)chunk * NSERIES + series;
    const size_t jstride = (size_t)NCHUNK * NSERIES;
    st[0 * jstride] = Sx_e;
    st[1 * jstride] = Sx_o;
    st[2 * jstride] = Sx2;
    st[3 * jstride] = Sa;
    st[4 * jstride] = Sa2;
    st[5 * jstride] = Sw_e;
    st[6 * jstride] = Sw_o;
    st[7 * jstride] = Sw2;
}

// ---------------- K2: reduce chunk partials -> cond per series ---------------
// 128 blocks x 256 threads; block handles 32 series, 8 threads per series
// (one per stat j). j = tid>>5 so a wave's 32 lanes read adjacent series.
__global__ __launch_bounds__(256)
void k2_finalize(const float* __restrict__ stats, float* __restrict__ condf) {
    const int j = threadIdx.x >> 5;          // stat index 0..7
    const int sl = threadIdx.x & 31;         // series local 0..31
    const int series = blockIdx.x * 32 + sl; // 0..4095
    const size_t jstride = (size_t)NCHUNK * NSERIES;

    const float* p = stats + j * jstride + series;
    float a = 0.f;
    #pragma unroll 8
    for (int k = 0; k < NCHUNK; ++k) a += p[(size_t)k * NSERIES];

    __shared__ float red[32][9];             // +1 pad
    red[sl][j] = a;
    __syncthreads();
    if (threadIdx.x < 32) {
        const int me = threadIdx.x;
        const float Sx_e = red[me][0], Sx_o = red[me][1], Sx2 = red[me][2];
        const float Sa = red[me][3], Sa2 = red[me][4];
        const float Sw_e = red[me][5], Sw_o = red[me][6], Sw2 = red[me][7];

        const float Sf = (float)SS;
        const float c_e = Sx_o / Sf;   // opposite-parity mean at even n
        const float c_o = Sx_e / Sf;   // at odd n
        const float halfS = 0.5f * Sf;
        const float sum_c = halfS * (c_e + c_o);
        const float sumsq_c = halfS * (c_e * c_e + c_o * c_o);

        // v1 = resid = w + c_p
        const float s1 = (Sw_e + Sw_o) + sum_c;
        const float q1 = Sw2 + 2.f * (c_e * Sw_e + c_o * Sw_o) + sumsq_c;
        const float var1 = (q1 - s1 * s1 / Sf) / (Sf - 1.f);
        // v2 = trend + resid = 0.5x + c_p
        const float s2 = 0.5f * (Sx_e + Sx_o) + sum_c;
        const float q2 = 0.25f * Sx2 + (c_e * Sx_e + c_o * Sx_o) + sumsq_c;
        const float var2 = (q2 - s2 * s2 / Sf) / (Sf - 1.f);
        // v3 = seasonal0 + resid = x - trend
        const float var3 = (Sa2 - Sa * Sa / Sf) / (Sf - 1.f);

        const float d_t = 1.f - var1 / (var2 + 1e-8f);
        const float d_s = 1.f - var1 / (var3 + 1e-8f);
        condf[blockIdx.x * 32 + me] = (d_t > 0.5f || d_s > 0.5f) ? 1.f : 0.f;
    }
}

// ---------------- K3: seasonal = cond ? x/(trend+eps) : x - trend ------------
__global__ __launch_bounds__(256)
void k3_seasonal(const float* __restrict__ x, const float* __restrict__ trend,
                 const float* __restrict__ condf, float* __restrict__ seasonal) {
    const int total4 = BB * SS * CC / 4;  // 4,194,304 float4s
    for (int q = blockIdx.x * blockDim.x + threadIdx.x; q < total4;
         q += gridDim.x * blockDim.x) {
        const int e = q * 4;
        const int b = e >> 19;          // / (SS*CC)
        const int c = e & (CC - 1);     // quad-aligned channel base
        const float4 x4 = *(const float4*)(x + e);
        const float4 t4 = *(const float4*)(trend + e);
        const float4 c4 = *(const float4*)(condf + b * CC + c);
        float4 o;
        o.x = (c4.x > 0.5f) ? x4.x / (t4.x + 1e-8f) : x4.x - t4.x;
        o.y = (c4.y > 0.5f) ? x4.y / (t4.y + 1e-8f) : x4.y - t4.y;
        o.z = (c4.z > 0.5f) ? x4.z / (t4.z + 1e-8f) : x4.z - t4.z;
        o.w = (c4.w > 0.5f) ? x4.w / (t4.w + 1e-8f) : x4.w - t4.w;
        *(float4*)(seasonal + e) = o;
    }
}

extern "C" void kernel_launch(void* const* d_in, const int* in_sizes, int n_in,
                              void* d_out, int out_size, void* d_ws, size_t ws_size,
                              hipStream_t stream) {
    const float* x = (const float*)d_in[0];
    float* out = (float*)d_out;
    float* trend = out;                               // output 0
    float* seasonal = out + (size_t)BB * SS * CC;     // output 1

    // stats scratch lives in the seasonal half of d_out (overwritten by K3);
    // only cond (16 KiB) uses d_ws.
    float* stats = seasonal;                          // 8*128*4096 floats = 16 MiB
    float* condf = (float*)d_ws;                      // 4096 floats

    k1_trend_stats<<<dim3(NBLK), dim3(CC), 0, stream>>>(x, trend, stats);
    k2_finalize<<<dim3(NSERIES / 32), dim3(256), 0, stream>>>(stats, condf);
    k3_seasonal<<<dim3(2048), dim3(256), 0, stream>>>(x, trend, condf, seasonal);
}

// Round 6
// 79.073 us; speedup vs baseline: 1.2123x; 1.0500x over previous
//
#include <hip/hip_runtime.h>

#define SS 4096
#define CC 128
#define BB 32
#define KW 25
#define PADW 12
#define CH 32               // rows per block chunk
#define CHR 16              // rows per thread (2 row-groups per block)
#define NCHUNK (SS / CH)    // 128
#define NSERIES (BB * CC)   // 4096
#define NBLK (BB * NCHUNK)  // 4096 K1 blocks
#define NXCD 8

typedef float f4v __attribute__((ext_vector_type(4)));  // native vector for nontemporal builtins

// ---------------- K1: trend (fp32 sequential window sum, ref order) + stats --
// float2 per thread: two independent dependency chains saturate VALU issue.
__global__ __launch_bounds__(128, 4)
void k1_trend_stats(const float* __restrict__ x, float* __restrict__ trend,
                    float* __restrict__ stats) {
    const int v = (blockIdx.x % NXCD) * (NBLK / NXCD) + blockIdx.x / NXCD;
    const int b = v / NCHUNK;
    const int chunk = v % NCHUNK;
    const int cp = threadIdx.x & 63;        // channel pair 0..63
    const int rg = threadIdx.x >> 6;        // row group 0/1
    const int s0 = chunk * CH + rg * CHR;   // even -> parity of s == i&1

    const float2* xs = (const float2*)(x + (size_t)b * SS * CC) + cp;   // row stride 64
    float2* ts = (float2*)(trend + (size_t)b * SS * CC) + cp;

    // win[j] = x[s0 - 12 + j], zero-padded
    float2 win[KW];
    #pragma unroll
    for (int j = 0; j < KW; ++j) {
        const int s = s0 - PADW + j;
        win[j] = (s >= 0 && s < SS) ? xs[s * 64] : make_float2(0.f, 0.f);
    }

    float2 Sx_e = {0.f, 0.f}, Sx_o = {0.f, 0.f}, Sx2 = {0.f, 0.f};
    float2 Sa = {0.f, 0.f}, Sa2 = {0.f, 0.f};
    float2 Sw_e = {0.f, 0.f}, Sw_o = {0.f, 0.f}, Sw2 = {0.f, 0.f};

    #pragma unroll
    for (int i = 0; i < CHR; ++i) {
        const int s = s0 + i;
        // prefetch next window element early (wave-uniform guard)
        const int sn = s + PADW + 1;
        float2 nxt = (sn < SS) ? xs[sn * 64] : make_float2(0.f, 0.f);

        // fp32 sequential sum, ascending window order == XLA reduce_window;
        // .x and .y are independent chains -> 2-way ILP.
        float ax = win[0].x, ay = win[0].y;
        #pragma unroll
        for (int j = 1; j < KW; ++j) { ax += win[j].x; ay += win[j].y; }
        float2 tf;
        tf.x = ax / 25.0f;              // IEEE f32 divide, matches sums / K
        tf.y = ay / 25.0f;
        ts[s * 64] = tf;

        const float2 xv = win[PADW];    // x[s]
        const float axx = xv.x - tf.x, axy = xv.y - tf.y;          // x - trend
        const float wx = 0.5f * xv.x - tf.x, wy = 0.5f * xv.y - tf.y;
        if (i & 1) { Sx_o.x += xv.x; Sx_o.y += xv.y; Sw_o.x += wx; Sw_o.y += wy; }
        else       { Sx_e.x += xv.x; Sx_e.y += xv.y; Sw_e.x += wx; Sw_e.y += wy; }
        Sx2.x += xv.x * xv.x;  Sx2.y += xv.y * xv.y;
        Sa.x  += axx;          Sa.y  += axy;
        Sa2.x += axx * axx;    Sa2.y += axy * axy;
        Sw2.x += wx * wx;      Sw2.y += wy * wy;

        // shift window (renamed away by the unroll)
        #pragma unroll
        for (int j = 0; j < KW - 1; ++j) win[j] = win[j + 1];
        win[KW - 1] = nxt;
    }

    // combine the two row-groups deterministically (rg0 += rg1), then write
    __shared__ float2 sred[8][64];
    if (rg == 1) {
        sred[0][cp] = Sx_e; sred[1][cp] = Sx_o; sred[2][cp] = Sx2;
        sred[3][cp] = Sa;   sred[4][cp] = Sa2;
        sred[5][cp] = Sw_e; sred[6][cp] = Sw_o; sred[7][cp] = Sw2;
    }
    __syncthreads();
    if (rg == 0) {
        Sx_e.x += sred[0][cp].x; Sx_e.y += sred[0][cp].y;
        Sx_o.x += sred[1][cp].x; Sx_o.y += sred[1][cp].y;
        Sx2.x  += sred[2][cp].x; Sx2.y  += sred[2][cp].y;
        Sa.x   += sred[3][cp].x; Sa.y   += sred[3][cp].y;
        Sa2.x  += sred[4][cp].x; Sa2.y  += sred[4][cp].y;
        Sw_e.x += sred[5][cp].x; Sw_e.y += sred[5][cp].y;
        Sw_o.x += sred[6][cp].x; Sw_o.y += sred[6][cp].y;
        Sw2.x  += sred[7][cp].x; Sw2.y  += sred[7][cp].y;

        const int series = b * CC + 2 * cp;          // even -> float2 aligned
        float* st = stats + (size_t)chunk * NSERIES + series;
        const size_t jstride = (size_t)NCHUNK * NSERIES;
        *(float2*)(st + 0 * jstride) = Sx_e;
        *(float2*)(st + 1 * jstride) = Sx_o;
        *(float2*)(st + 2 * jstride) = Sx2;
        *(float2*)(st + 3 * jstride) = Sa;
        *(float2*)(st + 4 * jstride) = Sa2;
        *(float2*)(st + 5 * jstride) = Sw_e;
        *(float2*)(st + 6 * jstride) = Sw_o;
        *(float2*)(st + 7 * jstride) = Sw2;
    }
}

// ---------------- K2: reduce chunk partials -> cond per series ---------------
__global__ __launch_bounds__(256)
void k2_finalize(const float* __restrict__ stats, float* __restrict__ condf) {
    const int j = threadIdx.x >> 5;          // stat index 0..7
    const int sl = threadIdx.x & 31;         // series local 0..31
    const int series = blockIdx.x * 32 + sl; // 0..4095
    const size_t jstride = (size_t)NCHUNK * NSERIES;

    const float* p = stats + j * jstride + series;
    float a = 0.f;
    #pragma unroll 8
    for (int k = 0; k < NCHUNK; ++k) a += p[(size_t)k * NSERIES];

    __shared__ float red[32][9];             // +1 pad
    red[sl][j] = a;
    __syncthreads();
    if (threadIdx.x < 32) {
        const int me = threadIdx.x;
        const float Sx_e = red[me][0], Sx_o = red[me][1], Sx2 = red[me][2];
        const float Sa = red[me][3], Sa2 = red[me][4];
        const float Sw_e = red[me][5], Sw_o = red[me][6], Sw2 = red[me][7];

        const float Sf = (float)SS;
        const float c_e = Sx_o / Sf;   // opposite-parity mean at even n
        const float c_o = Sx_e / Sf;   // at odd n
        const float halfS = 0.5f * Sf;
        const float sum_c = halfS * (c_e + c_o);
        const float sumsq_c = halfS * (c_e * c_e + c_o * c_o);

        // v1 = resid = w + c_p
        const float s1 = (Sw_e + Sw_o) + sum_c;
        const float q1 = Sw2 + 2.f * (c_e * Sw_e + c_o * Sw_o) + sumsq_c;
        const float var1 = (q1 - s1 * s1 / Sf) / (Sf - 1.f);
        // v2 = trend + resid = 0.5x + c_p
        const float s2 = 0.5f * (Sx_e + Sx_o) + sum_c;
        const float q2 = 0.25f * Sx2 + (c_e * Sx_e + c_o * Sx_o) + sumsq_c;
        const float var2 = (q2 - s2 * s2 / Sf) / (Sf - 1.f);
        // v3 = seasonal0 + resid = x - trend
        const float var3 = (Sa2 - Sa * Sa / Sf) / (Sf - 1.f);

        const float d_t = 1.f - var1 / (var2 + 1e-8f);
        const float d_s = 1.f - var1 / (var3 + 1e-8f);
        condf[blockIdx.x * 32 + me] = (d_t > 0.5f || d_s > 0.5f) ? 1.f : 0.f;
    }
}

// ---------------- K3: seasonal = cond ? x/(trend+eps) : x - trend ------------
__global__ __launch_bounds__(256)
void k3_seasonal(const float* __restrict__ x, const float* __restrict__ trend,
                 const float* __restrict__ condf, float* __restrict__ seasonal) {
    const int total4 = BB * SS * CC / 4;  // 4,194,304 float4s
    for (int q = blockIdx.x * blockDim.x + threadIdx.x; q < total4;
         q += gridDim.x * blockDim.x) {
        const int e = q * 4;
        const int b = e >> 19;          // / (SS*CC)
        const int c = e & (CC - 1);     // quad-aligned channel base
        // last-use data: nontemporal to avoid L2 pollution
        const f4v x4 = __builtin_nontemporal_load((const f4v*)(x + e));
        const f4v t4 = __builtin_nontemporal_load((const f4v*)(trend + e));
        const f4v c4 = *(const f4v*)(condf + b * CC + c);
        f4v o;
        o.x = (c4.x > 0.5f) ? x4.x / (t4.x + 1e-8f) : x4.x - t4.x;
        o.y = (c4.y > 0.5f) ? x4.y / (t4.y + 1e-8f) : x4.y - t4.y;
        o.z = (c4.z > 0.5f) ? x4.z / (t4.z + 1e-8f) : x4.z - t4.z;
        o.w = (c4.w > 0.5f) ? x4.w / (t4.w + 1e-8f) : x4.w - t4.w;
        __builtin_nontemporal_store(o, (f4v*)(seasonal + e));
    }
}

extern "C" void kernel_launch(void* const* d_in, const int* in_sizes, int n_in,
                              void* d_out, int out_size, void* d_ws, size_t ws_size,
                              hipStream_t stream) {
    const float* x = (const float*)d_in[0];
    float* out = (float*)d_out;
    float* trend = out;                               // output 0
    float* seasonal = out + (size_t)BB * SS * CC;     // output 1

    // stats scratch lives in the seasonal half of d_out (overwritten by K3);
    // only cond (16 KiB) uses d_ws.
    float* stats = seasonal;                          // 8*128*4096 floats = 16 MiB
    float* condf = (float*)d_ws;                      // 4096 floats

    k1_trend_stats<<<dim3(NBLK), dim3(128), 0, stream>>>(x, trend, stats);
    k2_finalize<<<dim3(NSERIES / 32), dim3(256), 0, stream>>>(stats, condf);
    k3_seasonal<<<dim3(2048), dim3(256), 0, stream>>>(x, trend, condf, seasonal);
}

// Round 7
// 75.634 us; speedup vs baseline: 1.2674x; 1.0455x over previous
//
#include <hip/hip_runtime.h>

#define SS 4096
#define CC 128
#define BB 32
#define KW 25
#define PADW 12
#define CH 32               // rows per block chunk
#define CHR 16              // rows per thread (2 row-groups per block)
#define PF 4                // prefetch depth (rows of MLP)
#define NCHUNK (SS / CH)    // 128
#define NSERIES (BB * CC)   // 4096
#define NBLK (BB * NCHUNK)  // 4096 K1 blocks
#define NXCD 8

typedef float f4v __attribute__((ext_vector_type(4)));  // native vector for nontemporal builtins

// ---------------- K1: trend (fp32 sequential window sum, ref order) + stats --
// float2 per thread (2 independent add chains); 4-deep row prefetch for MLP.
__global__ __launch_bounds__(128)
void k1_trend_stats(const float* __restrict__ x, float* __restrict__ trend,
                    float* __restrict__ stats) {
    const int v = (blockIdx.x % NXCD) * (NBLK / NXCD) + blockIdx.x / NXCD;
    const int b = v / NCHUNK;
    const int chunk = v % NCHUNK;
    const int cp = threadIdx.x & 63;        // channel pair 0..63
    const int rg = threadIdx.x >> 6;        // row group 0/1
    const int s0 = chunk * CH + rg * CHR;   // even -> parity of s == i&1

    const float2* xs = (const float2*)(x + (size_t)b * SS * CC) + cp;   // row stride 64
    float2* ts = (float2*)(trend + (size_t)b * SS * CC) + cp;

    // win[j] = x[s0 - 12 + j], zero-padded (25 independent loads, MLP=25)
    float2 win[KW];
    #pragma unroll
    for (int j = 0; j < KW; ++j) {
        const int s = s0 - PADW + j;
        win[j] = (s >= 0 && s < SS) ? xs[s * 64] : make_float2(0.f, 0.f);
    }

    float2 Sx_e = {0.f, 0.f}, Sx_o = {0.f, 0.f}, Sx2 = {0.f, 0.f};
    float2 Sa = {0.f, 0.f}, Sa2 = {0.f, 0.f};
    float2 Sw_e = {0.f, 0.f}, Sw_o = {0.f, 0.f}, Sw2 = {0.f, 0.f};

    #pragma unroll
    for (int g = 0; g < CHR / PF; ++g) {
        // issue PF row-loads up front (4 outstanding -> ~4x latency cover)
        float2 nxt[PF];
        #pragma unroll
        for (int t = 0; t < PF; ++t) {
            const int sn = s0 + g * PF + t + PADW + 1;
            nxt[t] = (sn < SS) ? xs[sn * 64] : make_float2(0.f, 0.f);
        }
        #pragma unroll
        for (int t = 0; t < PF; ++t) {
            const int i = g * PF + t;
            const int s = s0 + i;
            // fp32 sequential sum, ascending window order == XLA reduce_window
            float ax = win[0].x, ay = win[0].y;
            #pragma unroll
            for (int j = 1; j < KW; ++j) { ax += win[j].x; ay += win[j].y; }
            float2 tf;
            tf.x = ax / 25.0f;          // IEEE f32 divide, matches sums / K
            tf.y = ay / 25.0f;
            ts[s * 64] = tf;

            const float2 xv = win[PADW];    // x[s]
            const float axx = xv.x - tf.x, axy = xv.y - tf.y;      // x - trend
            const float wx = 0.5f * xv.x - tf.x, wy = 0.5f * xv.y - tf.y;
            if (i & 1) { Sx_o.x += xv.x; Sx_o.y += xv.y; Sw_o.x += wx; Sw_o.y += wy; }
            else       { Sx_e.x += xv.x; Sx_e.y += xv.y; Sw_e.x += wx; Sw_e.y += wy; }
            Sx2.x += xv.x * xv.x;  Sx2.y += xv.y * xv.y;
            Sa.x  += axx;          Sa.y  += axy;
            Sa2.x += axx * axx;    Sa2.y += axy * axy;
            Sw2.x += wx * wx;      Sw2.y += wy * wy;

            // shift window (renamed away by the unroll)
            #pragma unroll
            for (int j = 0; j < KW - 1; ++j) win[j] = win[j + 1];
            win[KW - 1] = nxt[t];
        }
    }

    // combine the two row-groups deterministically (rg0 += rg1), then write
    __shared__ float2 sred[8][64];
    if (rg == 1) {
        sred[0][cp] = Sx_e; sred[1][cp] = Sx_o; sred[2][cp] = Sx2;
        sred[3][cp] = Sa;   sred[4][cp] = Sa2;
        sred[5][cp] = Sw_e; sred[6][cp] = Sw_o; sred[7][cp] = Sw2;
    }
    __syncthreads();
    if (rg == 0) {
        Sx_e.x += sred[0][cp].x; Sx_e.y += sred[0][cp].y;
        Sx_o.x += sred[1][cp].x; Sx_o.y += sred[1][cp].y;
        Sx2.x  += sred[2][cp].x; Sx2.y  += sred[2][cp].y;
        Sa.x   += sred[3][cp].x; Sa.y   += sred[3][cp].y;
        Sa2.x  += sred[4][cp].x; Sa2.y  += sred[4][cp].y;
        Sw_e.x += sred[5][cp].x; Sw_e.y += sred[5][cp].y;
        Sw_o.x += sred[6][cp].x; Sw_o.y += sred[6][cp].y;
        Sw2.x  += sred[7][cp].x; Sw2.y  += sred[7][cp].y;

        const int series = b * CC + 2 * cp;          // even -> float2 aligned
        float* st = stats + (size_t)chunk * NSERIES + series;
        const size_t jstride = (size_t)NCHUNK * NSERIES;
        *(float2*)(st + 0 * jstride) = Sx_e;
        *(float2*)(st + 1 * jstride) = Sx_o;
        *(float2*)(st + 2 * jstride) = Sx2;
        *(float2*)(st + 3 * jstride) = Sa;
        *(float2*)(st + 4 * jstride) = Sa2;
        *(float2*)(st + 5 * jstride) = Sw_e;
        *(float2*)(st + 6 * jstride) = Sw_o;
        *(float2*)(st + 7 * jstride) = Sw2;
    }
}

// ---------------- K2: reduce chunk partials -> cond per series ---------------
__global__ __launch_bounds__(256)
void k2_finalize(const float* __restrict__ stats, float* __restrict__ condf) {
    const int j = threadIdx.x >> 5;          // stat index 0..7
    const int sl = threadIdx.x & 31;         // series local 0..31
    const int series = blockIdx.x * 32 + sl; // 0..4095
    const size_t jstride = (size_t)NCHUNK * NSERIES;

    const float* p = stats + j * jstride + series;
    float a = 0.f;
    #pragma unroll 8
    for (int k = 0; k < NCHUNK; ++k) a += p[(size_t)k * NSERIES];

    __shared__ float red[32][9];             // +1 pad
    red[sl][j] = a;
    __syncthreads();
    if (threadIdx.x < 32) {
        const int me = threadIdx.x;
        const float Sx_e = red[me][0], Sx_o = red[me][1], Sx2 = red[me][2];
        const float Sa = red[me][3], Sa2 = red[me][4];
        const float Sw_e = red[me][5], Sw_o = red[me][6], Sw2 = red[me][7];

        const float Sf = (float)SS;
        const float c_e = Sx_o / Sf;   // opposite-parity mean at even n
        const float c_o = Sx_e / Sf;   // at odd n
        const float halfS = 0.5f * Sf;
        const float sum_c = halfS * (c_e + c_o);
        const float sumsq_c = halfS * (c_e * c_e + c_o * c_o);

        // v1 = resid = w + c_p
        const float s1 = (Sw_e + Sw_o) + sum_c;
        const float q1 = Sw2 + 2.f * (c_e * Sw_e + c_o * Sw_o) + sumsq_c;
        const float var1 = (q1 - s1 * s1 / Sf) / (Sf - 1.f);
        // v2 = trend + resid = 0.5x + c_p
        const float s2 = 0.5f * (Sx_e + Sx_o) + sum_c;
        const float q2 = 0.25f * Sx2 + (c_e * Sx_e + c_o * Sx_o) + sumsq_c;
        const float var2 = (q2 - s2 * s2 / Sf) / (Sf - 1.f);
        // v3 = seasonal0 + resid = x - trend
        const float var3 = (Sa2 - Sa * Sa / Sf) / (Sf - 1.f);

        const float d_t = 1.f - var1 / (var2 + 1e-8f);
        const float d_s = 1.f - var1 / (var3 + 1e-8f);
        condf[blockIdx.x * 32 + me] = (d_t > 0.5f || d_s > 0.5f) ? 1.f : 0.f;
    }
}

// ---------------- K3: seasonal = cond ? x/(trend+eps) : x - trend ------------
// Contiguous 2048-quad tile per block; XCD swizzle aligned with K1's
// batch->XCD map (XCD k owns batches 4k..4k+3) for L2/L3 locality.
__global__ __launch_bounds__(256)
void k3_seasonal(const float* __restrict__ x, const float* __restrict__ trend,
                 const float* __restrict__ condf, float* __restrict__ seasonal) {
    const int vb = (blockIdx.x % NXCD) * 256 + blockIdx.x / NXCD;  // 2048 blocks
    const int qbase = vb * 2048;
    #pragma unroll
    for (int t = 0; t < 8; ++t) {
        const int q = qbase + t * 256 + threadIdx.x;
        const int e = q * 4;
        const int b = e >> 19;          // / (SS*CC)
        const int c = e & (CC - 1);     // quad-aligned channel base
        const f4v x4 = *(const f4v*)(x + e);          // cached: L3-resident
        const f4v t4 = *(const f4v*)(trend + e);      // cached: just written
        const f4v c4 = *(const f4v*)(condf + b * CC + c);
        f4v o;
        o.x = (c4.x > 0.5f) ? x4.x / (t4.x + 1e-8f) : x4.x - t4.x;
        o.y = (c4.y > 0.5f) ? x4.y / (t4.y + 1e-8f) : x4.y - t4.y;
        o.z = (c4.z > 0.5f) ? x4.z / (t4.z + 1e-8f) : x4.z - t4.z;
        o.w = (c4.w > 0.5f) ? x4.w / (t4.w + 1e-8f) : x4.w - t4.w;
        // seasonal is never re-read on device: nontemporal store
        __builtin_nontemporal_store(o, (f4v*)(seasonal + e));
    }
}

extern "C" void kernel_launch(void* const* d_in, const int* in_sizes, int n_in,
                              void* d_out, int out_size, void* d_ws, size_t ws_size,
                              hipStream_t stream) {
    const float* x = (const float*)d_in[0];
    float* out = (float*)d_out;
    float* trend = out;                               // output 0
    float* seasonal = out + (size_t)BB * SS * CC;     // output 1

    // stats scratch lives in the seasonal half of d_out (overwritten by K3);
    // only cond (16 KiB) uses d_ws.
    float* stats = seasonal;                          // 8*128*4096 floats = 16 MiB
    float* condf = (float*)d_ws;                      // 4096 floats

    k1_trend_stats<<<dim3(NBLK), dim3(128), 0, stream>>>(x, trend, stats);
    k2_finalize<<<dim3(NSERIES / 32), dim3(256), 0, stream>>>(stats, condf);
    k3_seasonal<<<dim3(2048), dim3(256), 0, stream>>>(x, trend, condf, seasonal);
}

// Round 8
// 71.478 us; speedup vs baseline: 1.3411x; 1.0581x over previous
//
#include <hip/hip_runtime.h>

#define SS 4096
#define CC 128
#define BB 32
#define KW 25
#define PADW 12
#define CH 32               // rows per block chunk
#define CHR 16              // rows per thread (2 row-groups per block)
#define NCHUNK (SS / CH)    // 128
#define NSERIES (BB * CC)   // 4096
#define NBLK (BB * NCHUNK)  // 4096 K1 blocks
#define NXCD 8

typedef float f4v __attribute__((ext_vector_type(4)));  // native vector for nontemporal builtins

// ---------------- K1: trend (fp32 sequential window sum, ref order) + stats --
// float2 per thread (2 independent add chains). ALL 16 row-loads issued
// upfront -> one latency exposure per wave instead of one per 4-row group.
__global__ __launch_bounds__(128)
void k1_trend_stats(const float* __restrict__ x, float* __restrict__ trend,
                    float* __restrict__ stats) {
    const int v = (blockIdx.x % NXCD) * (NBLK / NXCD) + blockIdx.x / NXCD;
    const int b = v / NCHUNK;
    const int chunk = v % NCHUNK;
    const int cp = threadIdx.x & 63;        // channel pair 0..63
    const int rg = threadIdx.x >> 6;        // row group 0/1
    const int s0 = chunk * CH + rg * CHR;   // even -> parity of s == i&1

    const float2* xs = (const float2*)(x + (size_t)b * SS * CC) + cp;   // row stride 64
    float2* ts = (float2*)(trend + (size_t)b * SS * CC) + cp;

    // win[j] = x[s0 - 12 + j], zero-padded (25 independent loads)
    float2 win[KW];
    #pragma unroll
    for (int j = 0; j < KW; ++j) {
        const int s = s0 - PADW + j;
        win[j] = (s >= 0 && s < SS) ? xs[s * 64] : make_float2(0.f, 0.f);
    }
    // all 16 future rows issued back-to-back: 16 outstanding loads, one stall
    float2 nxt[CHR];
    #pragma unroll
    for (int t = 0; t < CHR; ++t) {
        const int sn = s0 + t + PADW + 1;
        nxt[t] = (sn < SS) ? xs[sn * 64] : make_float2(0.f, 0.f);
    }

    float2 Sx_e = {0.f, 0.f}, Sx_o = {0.f, 0.f}, Sx2 = {0.f, 0.f};
    float2 Sa = {0.f, 0.f}, Sa2 = {0.f, 0.f};
    float2 Sw_e = {0.f, 0.f}, Sw_o = {0.f, 0.f}, Sw2 = {0.f, 0.f};

    #pragma unroll
    for (int i = 0; i < CHR; ++i) {
        const int s = s0 + i;
        // fp32 sequential sum, ascending window order == XLA reduce_window;
        // .x and .y are independent chains -> 2-way ILP.
        float ax = win[0].x, ay = win[0].y;
        #pragma unroll
        for (int j = 1; j < KW; ++j) { ax += win[j].x; ay += win[j].y; }
        float2 tf;
        tf.x = ax / 25.0f;              // IEEE f32 divide, matches sums / K
        tf.y = ay / 25.0f;
        ts[s * 64] = tf;

        const float2 xv = win[PADW];    // x[s]
        const float axx = xv.x - tf.x, axy = xv.y - tf.y;          // x - trend
        const float wx = 0.5f * xv.x - tf.x, wy = 0.5f * xv.y - tf.y;
        if (i & 1) { Sx_o.x += xv.x; Sx_o.y += xv.y; Sw_o.x += wx; Sw_o.y += wy; }
        else       { Sx_e.x += xv.x; Sx_e.y += xv.y; Sw_e.x += wx; Sw_e.y += wy; }
        Sx2.x += xv.x * xv.x;  Sx2.y += xv.y * xv.y;
        Sa.x  += axx;          Sa.y  += axy;
        Sa2.x += axx * axx;    Sa2.y += axy * axy;
        Sw2.x += wx * wx;      Sw2.y += wy * wy;

        // shift window (renamed away by the unroll)
        #pragma unroll
        for (int j = 0; j < KW - 1; ++j) win[j] = win[j + 1];
        win[KW - 1] = nxt[i];
    }

    // combine the two row-groups deterministically (rg0 += rg1), then write
    __shared__ float2 sred[8][64];
    if (rg == 1) {
        sred[0][cp] = Sx_e; sred[1][cp] = Sx_o; sred[2][cp] = Sx2;
        sred[3][cp] = Sa;   sred[4][cp] = Sa2;
        sred[5][cp] = Sw_e; sred[6][cp] = Sw_o; sred[7][cp] = Sw2;
    }
    __syncthreads();
    if (rg == 0) {
        Sx_e.x += sred[0][cp].x; Sx_e.y += sred[0][cp].y;
        Sx_o.x += sred[1][cp].x; Sx_o.y += sred[1][cp].y;
        Sx2.x  += sred[2][cp].x; Sx2.y  += sred[2][cp].y;
        Sa.x   += sred[3][cp].x; Sa.y   += sred[3][cp].y;
        Sa2.x  += sred[4][cp].x; Sa2.y  += sred[4][cp].y;
        Sw_e.x += sred[5][cp].x; Sw_e.y += sred[5][cp].y;
        Sw_o.x += sred[6][cp].x; Sw_o.y += sred[6][cp].y;
        Sw2.x  += sred[7][cp].x; Sw2.y  += sred[7][cp].y;

        const int series = b * CC + 2 * cp;          // even -> float2 aligned
        float* st = stats + (size_t)chunk * NSERIES + series;
        const size_t jstride = (size_t)NCHUNK * NSERIES;
        *(float2*)(st + 0 * jstride) = Sx_e;
        *(float2*)(st + 1 * jstride) = Sx_o;
        *(float2*)(st + 2 * jstride) = Sx2;
        *(float2*)(st + 3 * jstride) = Sa;
        *(float2*)(st + 4 * jstride) = Sa2;
        *(float2*)(st + 5 * jstride) = Sw_e;
        *(float2*)(st + 6 * jstride) = Sw_o;
        *(float2*)(st + 7 * jstride) = Sw2;
    }
}

// ---------------- K2a: chunk partials -> quarter partials --------------------
// 512 blocks (2/CU): block = (series-block sb of 32, quarter qq of 32 chunks).
__global__ __launch_bounds__(256)
void k2a_reduce(const float* __restrict__ stats, float* __restrict__ part) {
    const int sb = blockIdx.x >> 2;          // 0..127
    const int qq = blockIdx.x & 3;           // 0..3
    const int j  = threadIdx.x >> 5;         // stat 0..7
    const int sl = threadIdx.x & 31;
    const int series = sb * 32 + sl;
    const size_t jstride = (size_t)NCHUNK * NSERIES;

    const float* p = stats + j * jstride + (size_t)(qq * 32) * NSERIES + series;
    float a = 0.f;
    #pragma unroll 8
    for (int k = 0; k < 32; ++k) a += p[(size_t)k * NSERIES];
    part[((size_t)j * 4 + qq) * NSERIES + series] = a;
}

// ---------------- K2b: fold quarters + compute cond --------------------------
__global__ __launch_bounds__(256)
void k2b_finalize(const float* __restrict__ part, float* __restrict__ condf) {
    const int j = threadIdx.x >> 5;          // stat index 0..7
    const int sl = threadIdx.x & 31;         // series local 0..31
    const int series = blockIdx.x * 32 + sl; // 0..4095 (128 blocks)

    float a = 0.f;
    #pragma unroll
    for (int q = 0; q < 4; ++q) a += part[((size_t)j * 4 + q) * NSERIES + series];

    __shared__ float red[32][9];             // +1 pad
    red[sl][j] = a;
    __syncthreads();
    if (threadIdx.x < 32) {
        const int me = threadIdx.x;
        const float Sx_e = red[me][0], Sx_o = red[me][1], Sx2 = red[me][2];
        const float Sa = red[me][3], Sa2 = red[me][4];
        const float Sw_e = red[me][5], Sw_o = red[me][6], Sw2 = red[me][7];

        const float Sf = (float)SS;
        const float c_e = Sx_o / Sf;   // opposite-parity mean at even n
        const float c_o = Sx_e / Sf;   // at odd n
        const float halfS = 0.5f * Sf;
        const float sum_c = halfS * (c_e + c_o);
        const float sumsq_c = halfS * (c_e * c_e + c_o * c_o);

        // v1 = resid = w + c_p
        const float s1 = (Sw_e + Sw_o) + sum_c;
        const float q1 = Sw2 + 2.f * (c_e * Sw_e + c_o * Sw_o) + sumsq_c;
        const float var1 = (q1 - s1 * s1 / Sf) / (Sf - 1.f);
        // v2 = trend + resid = 0.5x + c_p
        const float s2 = 0.5f * (Sx_e + Sx_o) + sum_c;
        const float q2 = 0.25f * Sx2 + (c_e * Sx_e + c_o * Sx_o) + sumsq_c;
        const float var2 = (q2 - s2 * s2 / Sf) / (Sf - 1.f);
        // v3 = seasonal0 + resid = x - trend
        const float var3 = (Sa2 - Sa * Sa / Sf) / (Sf - 1.f);

        const float d_t = 1.f - var1 / (var2 + 1e-8f);
        const float d_s = 1.f - var1 / (var3 + 1e-8f);
        condf[blockIdx.x * 32 + me] = (d_t > 0.5f || d_s > 0.5f) ? 1.f : 0.f;
    }
}

// ---------------- K3: seasonal = cond ? x/(trend+eps) : x - trend ------------
__global__ __launch_bounds__(256)
void k3_seasonal(const float* __restrict__ x, const float* __restrict__ trend,
                 const float* __restrict__ condf, float* __restrict__ seasonal) {
    const int vb = (blockIdx.x % NXCD) * 256 + blockIdx.x / NXCD;  // 2048 blocks
    const int qbase = vb * 2048;
    #pragma unroll
    for (int t = 0; t < 8; ++t) {
        const int q = qbase + t * 256 + threadIdx.x;
        const int e = q * 4;
        const int b = e >> 19;          // / (SS*CC)
        const int c = e & (CC - 1);     // quad-aligned channel base
        const f4v x4 = *(const f4v*)(x + e);
        const f4v t4 = *(const f4v*)(trend + e);
        const f4v c4 = *(const f4v*)(condf + b * CC + c);
        f4v o;
        o.x = (c4.x > 0.5f) ? x4.x / (t4.x + 1e-8f) : x4.x - t4.x;
        o.y = (c4.y > 0.5f) ? x4.y / (t4.y + 1e-8f) : x4.y - t4.y;
        o.z = (c4.z > 0.5f) ? x4.z / (t4.z + 1e-8f) : x4.z - t4.z;
        o.w = (c4.w > 0.5f) ? x4.w / (t4.w + 1e-8f) : x4.w - t4.w;
        // seasonal is never re-read on device: nontemporal store
        __builtin_nontemporal_store(o, (f4v*)(seasonal + e));
    }
}

extern "C" void kernel_launch(void* const* d_in, const int* in_sizes, int n_in,
                              void* d_out, int out_size, void* d_ws, size_t ws_size,
                              hipStream_t stream) {
    const float* x = (const float*)d_in[0];
    float* out = (float*)d_out;
    float* trend = out;                               // output 0
    float* seasonal = out + (size_t)BB * SS * CC;     // output 1

    // scratch lives in the seasonal half of d_out (overwritten by K3);
    // only cond (16 KiB) uses d_ws.
    float* stats = seasonal;                          // 8*128*4096 floats = 16 MiB
    float* part = stats + (size_t)8 * NCHUNK / 8 * NSERIES * 8; // = stats + 4M floats
    float* condf = (float*)d_ws;                      // 4096 floats

    k1_trend_stats<<<dim3(NBLK), dim3(128), 0, stream>>>(x, trend, stats);
    k2a_reduce<<<dim3(512), dim3(256), 0, stream>>>(stats, part);
    k2b_finalize<<<dim3(NSERIES / 32), dim3(256), 0, stream>>>(part, condf);
    k3_seasonal<<<dim3(2048), dim3(256), 0, stream>>>(x, trend, condf, seasonal);
}

// Round 9
// 66.007 us; speedup vs baseline: 1.4522x; 1.0829x over previous
//
#include <hip/hip_runtime.h>

#define SS 4096
#define CC 128
#define BB 32
#define KW 25
#define PADW 12
#define CH 64               // rows per block chunk
#define SROWS (CH + KW - 1) // 88 staged rows
#define NCHUNK (SS / CH)    // 64
#define NSERIES (BB * CC)   // 4096
#define NBLK (BB * NCHUNK)  // 2048 K1 blocks
#define NXCD 8
#define STAGE_F4 (SROWS * CC / 4)   // 2816 float4s = 45056 B

typedef float f4v __attribute__((ext_vector_type(4)));

// ---------------- K1: LDS-staged trend + stats -------------------------------
// Block = 256 threads, 64 rows. Stage 88 rows (row block + 24 halo) via 11
// contiguous dwordx4 loads/thread -> LDS; rolling window computes from LDS.
__global__ __launch_bounds__(256)
void k1_trend_stats(const float* __restrict__ x, float* __restrict__ trend,
                    float* __restrict__ stats) {
    __shared__ f4v stage4[STAGE_F4];          // 44 KiB; reused for stat reduce

    const int v = (blockIdx.x % NXCD) * (NBLK / NXCD) + blockIdx.x / NXCD;
    const int b = v / NCHUNK;
    const int chunk = v % NCHUNK;
    const int s0 = chunk * CH;
    const int tid = threadIdx.x;
    const int cp = tid & 63;          // channel pair 0..63
    const int rg = tid >> 6;          // row group 0..3 (16 rows each)

    // ---- stage: rows s0-12 .. s0+75, zero-padded outside [0,SS) ----
    const int sbase = s0 - PADW;
    const float* xb = x + (size_t)b * SS * CC;
    f4v vals[11];
    #pragma unroll
    for (int t = 0; t < 11; ++t) {
        const int idx = t * 256 + tid;        // 0..2815
        const int rl = idx >> 5;              // local row 0..87
        const int col = (idx & 31) << 2;      // float offset in row
        const int srow = sbase + rl;
        const int crow = srow < 0 ? 0 : (srow >= SS ? SS - 1 : srow);
        vals[t] = *(const f4v*)(xb + (size_t)crow * CC + col);
    }
    #pragma unroll
    for (int t = 0; t < 11; ++t) {
        const int idx = t * 256 + tid;
        const int srow = sbase + (idx >> 5);
        if (srow < 0 || srow >= SS) vals[t] = (f4v){0.f, 0.f, 0.f, 0.f};
        stage4[idx] = vals[t];
    }
    __syncthreads();

    // ---- rolling window from LDS ----
    const float2* stg = (const float2*)stage4;
    float2* ts = (float2*)(trend + (size_t)b * SS * CC) + cp;
    const int r0 = rg * 16;                   // local row base (even)

    float2 win[KW];
    #pragma unroll
    for (int j = 0; j < KW; ++j) win[j] = stg[(r0 + j) * 64 + cp];

    float2 Sx_e = {0.f, 0.f}, Sx_o = {0.f, 0.f}, Sx2 = {0.f, 0.f};
    float2 Sa = {0.f, 0.f}, Sa2 = {0.f, 0.f};
    float2 Sw_e = {0.f, 0.f}, Sw_o = {0.f, 0.f}, Sw2 = {0.f, 0.f};

    #pragma unroll
    for (int i = 0; i < 16; ++i) {
        const int s = s0 + r0 + i;
        // fp32 sequential sum, ascending window order == XLA reduce_window;
        // .x and .y are independent chains -> 2-way ILP.
        float ax = win[0].x, ay = win[0].y;
        #pragma unroll
        for (int j = 1; j < KW; ++j) { ax += win[j].x; ay += win[j].y; }
        float2 tf;
        tf.x = ax / 25.0f;              // IEEE f32 divide, matches sums / K
        tf.y = ay / 25.0f;
        ts[s * 64] = tf;

        const float2 xv = win[PADW];    // x[s]
        const float axx = xv.x - tf.x, axy = xv.y - tf.y;      // x - trend
        const float wx = 0.5f * xv.x - tf.x, wy = 0.5f * xv.y - tf.y;
        if (i & 1) { Sx_o.x += xv.x; Sx_o.y += xv.y; Sw_o.x += wx; Sw_o.y += wy; }
        else       { Sx_e.x += xv.x; Sx_e.y += xv.y; Sw_e.x += wx; Sw_e.y += wy; }
        Sx2.x += xv.x * xv.x;  Sx2.y += xv.y * xv.y;
        Sa.x  += axx;          Sa.y  += axy;
        Sa2.x += axx * axx;    Sa2.y += axy * axy;
        Sw2.x += wx * wx;      Sw2.y += wy * wy;

        // shift window; fetch next LDS element (rows r0+i+25, guard last)
        #pragma unroll
        for (int j = 0; j < KW - 1; ++j) win[j] = win[j + 1];
        if (i < 15) win[KW - 1] = stg[(r0 + i + KW) * 64 + cp];
    }

    // ---- combine 4 row-groups deterministically (reuse stage LDS) ----
    __syncthreads();                          // all stage reads done
    float2* sr = (float2*)stage4;             // [g][j][cp], g=rg-1
    if (rg > 0) {
        float2* me = sr + (size_t)(rg - 1) * 512 + cp;
        me[0 * 64] = Sx_e; me[1 * 64] = Sx_o; me[2 * 64] = Sx2;
        me[3 * 64] = Sa;   me[4 * 64] = Sa2;
        me[5 * 64] = Sw_e; me[6 * 64] = Sw_o; me[7 * 64] = Sw2;
    }
    __syncthreads();
    if (rg == 0) {
        #pragma unroll
        for (int g = 0; g < 3; ++g) {
            const float2* gp = sr + (size_t)g * 512 + cp;
            Sx_e.x += gp[0*64].x; Sx_e.y += gp[0*64].y;
            Sx_o.x += gp[1*64].x; Sx_o.y += gp[1*64].y;
            Sx2.x  += gp[2*64].x; Sx2.y  += gp[2*64].y;
            Sa.x   += gp[3*64].x; Sa.y   += gp[3*64].y;
            Sa2.x  += gp[4*64].x; Sa2.y  += gp[4*64].y;
            Sw_e.x += gp[5*64].x; Sw_e.y += gp[5*64].y;
            Sw_o.x += gp[6*64].x; Sw_o.y += gp[6*64].y;
            Sw2.x  += gp[7*64].x; Sw2.y  += gp[7*64].y;
        }
        const int series = b * CC + 2 * cp;   // float2-aligned
        float* st = stats + (size_t)chunk * NSERIES + series;
        const size_t jstride = (size_t)NCHUNK * NSERIES;
        *(float2*)(st + 0 * jstride) = Sx_e;
        *(float2*)(st + 1 * jstride) = Sx_o;
        *(float2*)(st + 2 * jstride) = Sx2;
        *(float2*)(st + 3 * jstride) = Sa;
        *(float2*)(st + 4 * jstride) = Sa2;
        *(float2*)(st + 5 * jstride) = Sw_e;
        *(float2*)(st + 6 * jstride) = Sw_o;
        *(float2*)(st + 7 * jstride) = Sw2;
    }
}

// ---------------- K2a: chunk partials -> quarter partials --------------------
// 512 blocks: block = (series-block sb of 32, quarter qq of 16 chunks).
__global__ __launch_bounds__(256)
void k2a_reduce(const float* __restrict__ stats, float* __restrict__ part) {
    const int sb = blockIdx.x >> 2;          // 0..127
    const int qq = blockIdx.x & 3;           // 0..3
    const int j  = threadIdx.x >> 5;         // stat 0..7
    const int sl = threadIdx.x & 31;
    const int series = sb * 32 + sl;
    const size_t jstride = (size_t)NCHUNK * NSERIES;

    const float* p = stats + j * jstride + (size_t)(qq * 16) * NSERIES + series;
    float a = 0.f;
    #pragma unroll 8
    for (int k = 0; k < 16; ++k) a += p[(size_t)k * NSERIES];
    part[((size_t)j * 4 + qq) * NSERIES + series] = a;
}

// ---------------- K2b: fold quarters + compute cond --------------------------
__global__ __launch_bounds__(256)
void k2b_finalize(const float* __restrict__ part, float* __restrict__ condf) {
    const int j = threadIdx.x >> 5;          // stat index 0..7
    const int sl = threadIdx.x & 31;         // series local 0..31
    const int series = blockIdx.x * 32 + sl; // 0..4095 (128 blocks)

    float a = 0.f;
    #pragma unroll
    for (int q = 0; q < 4; ++q) a += part[((size_t)j * 4 + q) * NSERIES + series];

    __shared__ float red[32][9];             // +1 pad
    red[sl][j] = a;
    __syncthreads();
    if (threadIdx.x < 32) {
        const int me = threadIdx.x;
        const float Sx_e = red[me][0], Sx_o = red[me][1], Sx2 = red[me][2];
        const float Sa = red[me][3], Sa2 = red[me][4];
        const float Sw_e = red[me][5], Sw_o = red[me][6], Sw2 = red[me][7];

        const float Sf = (float)SS;
        const float c_e = Sx_o / Sf;   // opposite-parity mean at even n
        const float c_o = Sx_e / Sf;   // at odd n
        const float halfS = 0.5f * Sf;
        const float sum_c = halfS * (c_e + c_o);
        const float sumsq_c = halfS * (c_e * c_e + c_o * c_o);

        // v1 = resid = w + c_p
        const float s1 = (Sw_e + Sw_o) + sum_c;
        const float q1 = Sw2 + 2.f * (c_e * Sw_e + c_o * Sw_o) + sumsq_c;
        const float var1 = (q1 - s1 * s1 / Sf) / (Sf - 1.f);
        // v2 = trend + resid = 0.5x + c_p
        const float s2 = 0.5f * (Sx_e + Sx_o) + sum_c;
        const float q2 = 0.25f * Sx2 + (c_e * Sx_e + c_o * Sx_o) + sumsq_c;
        const float var2 = (q2 - s2 * s2 / Sf) / (Sf - 1.f);
        // v3 = seasonal0 + resid = x - trend
        const float var3 = (Sa2 - Sa * Sa / Sf) / (Sf - 1.f);

        const float d_t = 1.f - var1 / (var2 + 1e-8f);
        const float d_s = 1.f - var1 / (var3 + 1e-8f);
        condf[blockIdx.x * 32 + me] = (d_t > 0.5f || d_s > 0.5f) ? 1.f : 0.f;
    }
}

// ---------------- K3: seasonal = cond ? x/(trend+eps) : x - trend ------------
__global__ __launch_bounds__(256)
void k3_seasonal(const float* __restrict__ x, const float* __restrict__ trend,
                 const float* __restrict__ condf, float* __restrict__ seasonal) {
    const int vb = (blockIdx.x % NXCD) * 256 + blockIdx.x / NXCD;  // 2048 blocks
    const int qbase = vb * 2048;
    #pragma unroll
    for (int t = 0; t < 8; ++t) {
        const int q = qbase + t * 256 + threadIdx.x;
        const int e = q * 4;
        const int b = e >> 19;          // / (SS*CC)
        const int c = e & (CC - 1);     // quad-aligned channel base
        const f4v x4 = *(const f4v*)(x + e);
        const f4v t4 = *(const f4v*)(trend + e);
        const f4v c4 = *(const f4v*)(condf + b * CC + c);
        f4v o;
        o.x = (c4.x > 0.5f) ? x4.x / (t4.x + 1e-8f) : x4.x - t4.x;
        o.y = (c4.y > 0.5f) ? x4.y / (t4.y + 1e-8f) : x4.y - t4.y;
        o.z = (c4.z > 0.5f) ? x4.z / (t4.z + 1e-8f) : x4.z - t4.z;
        o.w = (c4.w > 0.5f) ? x4.w / (t4.w + 1e-8f) : x4.w - t4.w;
        // seasonal is never re-read on device: nontemporal store
        __builtin_nontemporal_store(o, (f4v*)(seasonal + e));
    }
}

extern "C" void kernel_launch(void* const* d_in, const int* in_sizes, int n_in,
                              void* d_out, int out_size, void* d_ws, size_t ws_size,
                              hipStream_t stream) {
    const float* x = (const float*)d_in[0];
    float* out = (float*)d_out;
    float* trend = out;                               // output 0
    float* seasonal = out + (size_t)BB * SS * CC;     // output 1

    // scratch lives in the seasonal half of d_out (overwritten by K3);
    // only cond (16 KiB) uses d_ws.
    float* stats = seasonal;                          // 8*64*4096 floats = 8 MiB
    float* part = stats + (size_t)8 * NCHUNK * NSERIES; // after stats
    float* condf = (float*)d_ws;                      // 4096 floats

    k1_trend_stats<<<dim3(NBLK), dim3(256), 0, stream>>>(x, trend, stats);
    k2a_reduce<<<dim3(512), dim3(256), 0, stream>>>(stats, part);
    k2b_finalize<<<dim3(NSERIES / 32), dim3(256), 0, stream>>>(part, condf);
    k3_seasonal<<<dim3(2048), dim3(256), 0, stream>>>(x, trend, condf, seasonal);
}

// Round 10
// 63.613 us; speedup vs baseline: 1.5069x; 1.0376x over previous
//
#include <hip/hip_runtime.h>

#define SS 4096
#define CC 128
#define BB 32
#define KW 25
#define PADW 12
#define CH 64               // rows per chunk
#define SROWS (CH + KW - 1) // 88 staged rows per chunk
#define CPB 8               // chunks per block (persistent)
#define NCHUNK (SS / CH)    // 64
#define NSERIES (BB * CC)   // 4096
#define NBLK (BB * NCHUNK / CPB)  // 256 K1 blocks = 1 per CU
#define STAGE_F4 (SROWS * CC / 4) // 2816 float4s = 44 KiB per buffer
#define NXCD 8

typedef float f4v __attribute__((ext_vector_type(4)));

// ---------------- K1: persistent, double-buffered trend + stats --------------
// 256 blocks x 512 threads; block owns one 512-row quarter of one batch.
// Per chunk: issue next chunk's global loads -> compute current from LDS ->
// commit loaded regs to the other LDS buffer. HBM stays saturated.
__global__ __launch_bounds__(512)
void k1_trend_stats(const float* __restrict__ x, float* __restrict__ trend,
                    float* __restrict__ stats) {
    __shared__ f4v stage[2][STAGE_F4];        // 88 KiB
    __shared__ float2 sred[7][8][64];         // 28 KiB stats reduce

    const int blk = blockIdx.x;               // 0..255
    const int b = blk >> 3;                   // batch
    const int q = blk & 7;                    // quarter (512 rows)
    const int tid = threadIdx.x;
    const int cp = tid & 63;                  // channel pair 0..63
    const int rg = tid >> 6;                  // row group 0..7 (8 rows/chunk)
    const float* __restrict__ xb = x + (size_t)b * SS * CC;
    float2* __restrict__ tb = (float2*)(trend + (size_t)b * SS * CC);

    f4v vals[6];
    auto issue = [&](int c) {                 // global -> regs (6 dwordx4)
        const int sbase = q * (CPB * CH) + c * CH - PADW;
        #pragma unroll
        for (int t = 0; t < 6; ++t) {
            const int idx = t * 512 + tid;
            if (idx < STAGE_F4) {
                const int srow = sbase + (idx >> 5);
                const int crow = srow < 0 ? 0 : (srow >= SS ? SS - 1 : srow);
                vals[t] = *(const f4v*)(xb + (size_t)crow * CC + ((idx & 31) << 2));
            }
        }
    };
    auto commit = [&](int c, int buf) {       // regs -> LDS (zero-pad edges)
        const int sbase = q * (CPB * CH) + c * CH - PADW;
        #pragma unroll
        for (int t = 0; t < 6; ++t) {
            const int idx = t * 512 + tid;
            if (idx < STAGE_F4) {
                f4v w = vals[t];
                const int srow = sbase + (idx >> 5);
                if (srow < 0 || srow >= SS) w = (f4v){0.f, 0.f, 0.f, 0.f};
                stage[buf][idx] = w;
            }
        }
    };

    // prologue: fill buffer 0 with chunk 0
    issue(0);
    commit(0, 0);

    float2 Sx_e = {0.f,0.f}, Sx_o = {0.f,0.f}, Sx2 = {0.f,0.f};
    float2 Sa = {0.f,0.f}, Sa2 = {0.f,0.f};
    float2 Sw_e = {0.f,0.f}, Sw_o = {0.f,0.f}, Sw2 = {0.f,0.f};

    for (int c = 0; c < CPB; ++c) {
        __syncthreads();                      // stage[c&1] ready (lgkm drained)
        const int cur = c & 1;
        if (c + 1 < CPB) issue(c + 1);        // overlap loads with compute

        const int S0 = q * (CPB * CH) + c * CH;
        const int r0 = rg * 8;                // local row base (even)
        const float2* stg = (const float2*)stage[cur];

        float2 win[KW];
        #pragma unroll
        for (int j = 0; j < KW; ++j) win[j] = stg[(r0 + j) * 64 + cp];

        #pragma unroll
        for (int i = 0; i < 8; ++i) {
            // fp32 sequential sum, ascending window order == XLA reduce_window
            float ax = win[0].x, ay = win[0].y;
            #pragma unroll
            for (int j = 1; j < KW; ++j) { ax += win[j].x; ay += win[j].y; }
            float2 tf;
            tf.x = ax / 25.0f;                // IEEE f32 divide, matches sums/K
            tf.y = ay / 25.0f;
            tb[(S0 + r0 + i) * 64 + cp] = tf;

            const float2 xv = win[PADW];      // x[s]
            const float axx = xv.x - tf.x, axy = xv.y - tf.y;   // x - trend
            const float wx = 0.5f * xv.x - tf.x, wy = 0.5f * xv.y - tf.y;
            if (i & 1) { Sx_o.x += xv.x; Sx_o.y += xv.y; Sw_o.x += wx; Sw_o.y += wy; }
            else       { Sx_e.x += xv.x; Sx_e.y += xv.y; Sw_e.x += wx; Sw_e.y += wy; }
            Sx2.x += xv.x * xv.x;  Sx2.y += xv.y * xv.y;
            Sa.x  += axx;          Sa.y  += axy;
            Sa2.x += axx * axx;    Sa2.y += axy * axy;
            Sw2.x += wx * wx;      Sw2.y += wy * wy;

            #pragma unroll
            for (int j = 0; j < KW - 1; ++j) win[j] = win[j + 1];
            if (i < 7) win[KW - 1] = stg[(r0 + i + KW) * 64 + cp];
        }

        if (c + 1 < CPB) commit(c + 1, cur ^ 1);  // regs -> other buffer
    }

    // ---- combine 8 row-groups deterministically ----
    if (rg > 0) {
        float2* me = &sred[rg - 1][0][cp];
        me[0*64] = Sx_e; me[1*64] = Sx_o; me[2*64] = Sx2;
        me[3*64] = Sa;   me[4*64] = Sa2;
        me[5*64] = Sw_e; me[6*64] = Sw_o; me[7*64] = Sw2;
    }
    __syncthreads();
    if (rg == 0) {
        #pragma unroll
        for (int g = 0; g < 7; ++g) {
            const float2* gp = &sred[g][0][cp];
            Sx_e.x += gp[0*64].x; Sx_e.y += gp[0*64].y;
            Sx_o.x += gp[1*64].x; Sx_o.y += gp[1*64].y;
            Sx2.x  += gp[2*64].x; Sx2.y  += gp[2*64].y;
            Sa.x   += gp[3*64].x; Sa.y   += gp[3*64].y;
            Sa2.x  += gp[4*64].x; Sa2.y  += gp[4*64].y;
            Sw_e.x += gp[5*64].x; Sw_e.y += gp[5*64].y;
            Sw_o.x += gp[6*64].x; Sw_o.y += gp[6*64].y;
            Sw2.x  += gp[7*64].x; Sw2.y  += gp[7*64].y;
        }
        const int series = b * CC + 2 * cp;   // float2-aligned
        float* st = stats + (size_t)q * NSERIES + series;
        const size_t jstride = (size_t)CPB * NSERIES;   // 8 quarters per stat
        *(float2*)(st + 0 * jstride) = Sx_e;
        *(float2*)(st + 1 * jstride) = Sx_o;
        *(float2*)(st + 2 * jstride) = Sx2;
        *(float2*)(st + 3 * jstride) = Sa;
        *(float2*)(st + 4 * jstride) = Sa2;
        *(float2*)(st + 5 * jstride) = Sw_e;
        *(float2*)(st + 6 * jstride) = Sw_o;
        *(float2*)(st + 7 * jstride) = Sw2;
    }
}

// ---------------- K2: fold 8 quarter-partials + compute cond -----------------
__global__ __launch_bounds__(256)
void k2_finalize(const float* __restrict__ stats, float* __restrict__ condf) {
    const int j = threadIdx.x >> 5;          // stat index 0..7
    const int sl = threadIdx.x & 31;         // series local 0..31
    const int series = blockIdx.x * 32 + sl; // 0..4095 (128 blocks)

    float a = 0.f;
    #pragma unroll
    for (int k = 0; k < 8; ++k)
        a += stats[((size_t)j * 8 + k) * NSERIES + series];

    __shared__ float red[32][9];             // +1 pad
    red[sl][j] = a;
    __syncthreads();
    if (threadIdx.x < 32) {
        const int me = threadIdx.x;
        const float Sx_e = red[me][0], Sx_o = red[me][1], Sx2 = red[me][2];
        const float Sa = red[me][3], Sa2 = red[me][4];
        const float Sw_e = red[me][5], Sw_o = red[me][6], Sw2 = red[me][7];

        const float Sf = (float)SS;
        const float c_e = Sx_o / Sf;   // opposite-parity mean at even n
        const float c_o = Sx_e / Sf;   // at odd n
        const float halfS = 0.5f * Sf;
        const float sum_c = halfS * (c_e + c_o);
        const float sumsq_c = halfS * (c_e * c_e + c_o * c_o);

        // v1 = resid = w + c_p
        const float s1 = (Sw_e + Sw_o) + sum_c;
        const float q1 = Sw2 + 2.f * (c_e * Sw_e + c_o * Sw_o) + sumsq_c;
        const float var1 = (q1 - s1 * s1 / Sf) / (Sf - 1.f);
        // v2 = trend + resid = 0.5x + c_p
        const float s2 = 0.5f * (Sx_e + Sx_o) + sum_c;
        const float q2 = 0.25f * Sx2 + (c_e * Sx_e + c_o * Sx_o) + sumsq_c;
        const float var2 = (q2 - s2 * s2 / Sf) / (Sf - 1.f);
        // v3 = seasonal0 + resid = x - trend
        const float var3 = (Sa2 - Sa * Sa / Sf) / (Sf - 1.f);

        const float d_t = 1.f - var1 / (var2 + 1e-8f);
        const float d_s = 1.f - var1 / (var3 + 1e-8f);
        condf[blockIdx.x * 32 + me] = (d_t > 0.5f || d_s > 0.5f) ? 1.f : 0.f;
    }
}

// ---------------- K3: seasonal = cond ? x/(trend+eps) : x - trend ------------
__global__ __launch_bounds__(256)
void k3_seasonal(const float* __restrict__ x, const float* __restrict__ trend,
                 const float* __restrict__ condf, float* __restrict__ seasonal) {
    const int vb = (blockIdx.x % NXCD) * 256 + blockIdx.x / NXCD;  // 2048 blocks
    const int qbase = vb * 2048;
    #pragma unroll
    for (int t = 0; t < 8; ++t) {
        const int q = qbase + t * 256 + threadIdx.x;
        const int e = q * 4;
        const int b = e >> 19;          // / (SS*CC)
        const int c = e & (CC - 1);     // quad-aligned channel base
        const f4v x4 = *(const f4v*)(x + e);
        const f4v t4 = *(const f4v*)(trend + e);
        const f4v c4 = *(const f4v*)(condf + b * CC + c);
        f4v o;
        o.x = (c4.x > 0.5f) ? x4.x / (t4.x + 1e-8f) : x4.x - t4.x;
        o.y = (c4.y > 0.5f) ? x4.y / (t4.y + 1e-8f) : x4.y - t4.y;
        o.z = (c4.z > 0.5f) ? x4.z / (t4.z + 1e-8f) : x4.z - t4.z;
        o.w = (c4.w > 0.5f) ? x4.w / (t4.w + 1e-8f) : x4.w - t4.w;
        // seasonal is never re-read on device: nontemporal store
        __builtin_nontemporal_store(o, (f4v*)(seasonal + e));
    }
}

extern "C" void kernel_launch(void* const* d_in, const int* in_sizes, int n_in,
                              void* d_out, int out_size, void* d_ws, size_t ws_size,
                              hipStream_t stream) {
    const float* x = (const float*)d_in[0];
    float* out = (float*)d_out;
    float* trend = out;                               // output 0
    float* seasonal = out + (size_t)BB * SS * CC;     // output 1

    // stats scratch (1 MiB) lives in the seasonal half (overwritten by K3);
    // cond (16 KiB) uses d_ws.
    float* stats = seasonal;                          // 8*8*4096 floats
    float* condf = (float*)d_ws;                      // 4096 floats

    k1_trend_stats<<<dim3(NBLK), dim3(512), 0, stream>>>(x, trend, stats);
    k2_finalize<<<dim3(NSERIES / 32), dim3(256), 0, stream>>>(stats, condf);
    k3_seasonal<<<dim3(2048), dim3(256), 0, stream>>>(x, trend, condf, seasonal);
}

// Round 11
// 63.308 us; speedup vs baseline: 1.5141x; 1.0048x over previous
//
#include <hip/hip_runtime.h>

#define SS 4096
#define CC 128
#define BB 32
#define KW 25
#define PADW 12
#define CH 64               // rows per chunk (KB)
#define SROWS (CH + KW - 1) // 88 staged rows per chunk
#define CPB 8               // chunks per block (KB persistent)
#define NSERIES (BB * CC)   // 4096
#define STAGE_F4 (SROWS * CC / 4) // 2816 float4s = 44 KiB per buffer
#define NKCH 64             // KA chunks per series (64 rows each)

typedef float f4v __attribute__((ext_vector_type(4)));
typedef float f2v __attribute__((ext_vector_type(2)));

// ---------------- KA: stats only (fp64 rolling trend, no writes but stats) ---
// 512 blocks x 256 threads; thread = (chunk k, batch b, channel-pair c2),
// 64 rows per thread, streaming float2 loads, 8-deep row prefetch.
__global__ __launch_bounds__(256)
void ka_stats(const float* __restrict__ x, float* __restrict__ stats) {
    const int T = blockIdx.x * 256 + threadIdx.x;
    const int c2 = T & 63;
    const int b = (T >> 6) & 31;
    const int k = T >> 11;            // 0..63
    const int s0 = k * 64;            // even -> parity of s == i&1
    const f2v* xs = (const f2v*)(x + (size_t)b * SS * CC) + c2;

    f2v win[KW];
    double Wx = 0.0, Wy = 0.0;
    #pragma unroll
    for (int j = 0; j < KW; ++j) {
        const int s = s0 - PADW + j;
        const f2v v = (s >= 0 && s < SS) ? xs[s * 64] : (f2v){0.f, 0.f};
        win[j] = v;
        Wx += (double)v.x; Wy += (double)v.y;
    }

    f2v Sx_e = {0,0}, Sx_o = {0,0}, Sx2 = {0,0};
    f2v St_e = {0,0}, St_o = {0,0}, St2 = {0,0}, Sxt = {0,0};

    #pragma unroll
    for (int g = 0; g < 8; ++g) {
        f2v nx[8];                    // prefetch 8 rows ahead
        #pragma unroll
        for (int t = 0; t < 8; ++t) {
            const int sn = s0 + g * 8 + t + PADW + 1;
            nx[t] = (sn < SS) ? xs[sn * 64] : (f2v){0.f, 0.f};
        }
        #pragma unroll
        for (int t = 0; t < 8; ++t) {
            const int i = g * 8 + t;
            f2v tf;
            tf.x = (float)(Wx * (1.0 / 25.0));   // fp64-rolling trend: stats
            tf.y = (float)(Wy * (1.0 / 25.0));   // only need ~1e-6 accuracy
            const f2v xv = win[PADW];
            if (i & 1) { Sx_o.x += xv.x; Sx_o.y += xv.y; St_o.x += tf.x; St_o.y += tf.y; }
            else       { Sx_e.x += xv.x; Sx_e.y += xv.y; St_e.x += tf.x; St_e.y += tf.y; }
            Sx2.x += xv.x * xv.x;  Sx2.y += xv.y * xv.y;
            St2.x += tf.x * tf.x;  St2.y += tf.y * tf.y;
            Sxt.x += xv.x * tf.x;  Sxt.y += xv.y * tf.y;
            Wx += (double)nx[t].x - (double)win[0].x;
            Wy += (double)nx[t].y - (double)win[0].y;
            #pragma unroll
            for (int j = 0; j < KW - 1; ++j) win[j] = win[j + 1];
            win[KW - 1] = nx[t];
        }
    }

    const int series = b * CC + 2 * c2;      // float2-aligned
    float* st = stats + (size_t)k * NSERIES + series;
    const size_t jstride = (size_t)NKCH * NSERIES;
    *(f2v*)(st + 0 * jstride) = Sx_e;
    *(f2v*)(st + 1 * jstride) = Sx_o;
    *(f2v*)(st + 2 * jstride) = Sx2;
    *(f2v*)(st + 3 * jstride) = St_e;
    *(f2v*)(st + 4 * jstride) = St_o;
    *(f2v*)(st + 5 * jstride) = St2;
    *(f2v*)(st + 6 * jstride) = Sxt;
}

// ---------------- K2: fold 64 chunk-partials + compute cond ------------------
__global__ __launch_bounds__(256)
void k2_finalize(const float* __restrict__ stats, float* __restrict__ condf) {
    const int j = threadIdx.x >> 5;          // stat index 0..7 (7 used)
    const int sl = threadIdx.x & 31;
    const int series = blockIdx.x * 32 + sl; // 0..4095 (128 blocks)
    const size_t jstride = (size_t)NKCH * NSERIES;

    __shared__ float red[32][8];
    if (j < 7) {
        const float* p = stats + j * jstride + series;
        float a = 0.f;
        #pragma unroll 8
        for (int k = 0; k < NKCH; ++k) a += p[(size_t)k * NSERIES];
        red[sl][j] = a;
    }
    __syncthreads();
    if (threadIdx.x < 32) {
        const int me = threadIdx.x;
        const float Sx_e = red[me][0], Sx_o = red[me][1], Sx2 = red[me][2];
        const float St_e = red[me][3], St_o = red[me][4], St2 = red[me][5];
        const float Sxt = red[me][6];

        const float Sf = (float)SS;
        const float halfS = 0.5f * Sf;
        const float c_e = Sx_o / Sf;         // opposite-parity mean at even n
        const float c_o = Sx_e / Sf;
        const float sum_c = halfS * (c_e + c_o);
        const float sumsq_c = halfS * (c_e * c_e + c_o * c_o);

        const float Sw_e = 0.5f * Sx_e - St_e;
        const float Sw_o = 0.5f * Sx_o - St_o;
        const float Sw2 = 0.25f * Sx2 - Sxt + St2;

        // v1 = resid = w + c_p
        const float s1 = (Sw_e + Sw_o) + sum_c;
        const float q1 = Sw2 + 2.f * (c_e * Sw_e + c_o * Sw_o) + sumsq_c;
        const float var1 = (q1 - s1 * s1 / Sf) / (Sf - 1.f);
        // v2 = trend + resid = 0.5x + c_p
        const float s2 = 0.5f * (Sx_e + Sx_o) + sum_c;
        const float q2 = 0.25f * Sx2 + (c_e * Sx_e + c_o * Sx_o) + sumsq_c;
        const float var2 = (q2 - s2 * s2 / Sf) / (Sf - 1.f);
        // v3 = seasonal0 + resid = x - trend
        const float Sa = (Sx_e + Sx_o) - (St_e + St_o);
        const float Sa2 = Sx2 - 2.f * Sxt + St2;
        const float var3 = (Sa2 - Sa * Sa / Sf) / (Sf - 1.f);

        const float d_t = 1.f - var1 / (var2 + 1e-8f);
        const float d_s = 1.f - var1 / (var3 + 1e-8f);
        condf[blockIdx.x * 32 + me] = (d_t > 0.5f || d_s > 0.5f) ? 1.f : 0.f;
    }
}

// ---------------- KB: bit-exact trend + seasonal, one pass -------------------
// 256 blocks x 512 threads, persistent over 8 chunks, double-buffered LDS.
// x reads are L3 hits (KA just streamed x); writes are the HBM floor.
__global__ __launch_bounds__(512)
void kb_outputs(const float* __restrict__ x, const float* __restrict__ condf,
                float* __restrict__ trend, float* __restrict__ seasonal) {
    __shared__ f4v stage[2][STAGE_F4];        // 88 KiB

    const int blk = blockIdx.x;               // 0..255
    const int b = blk >> 3;                   // batch
    const int q = blk & 7;                    // quarter (512 rows)
    const int tid = threadIdx.x;
    const int cp = tid & 63;                  // channel pair
    const int rg = tid >> 6;                  // row group 0..7 (8 rows/chunk)
    const float* __restrict__ xb = x + (size_t)b * SS * CC;
    f2v* __restrict__ tb = (f2v*)(trend + (size_t)b * SS * CC);
    f2v* __restrict__ sv = (f2v*)(seasonal + (size_t)b * SS * CC);
    const f2v cnd = ((const f2v*)condf)[b * 64 + cp];

    f4v vals[6];
    auto issue = [&](int c) {                 // global -> regs (6 dwordx4)
        const int sbase = q * (CPB * CH) + c * CH - PADW;
        #pragma unroll
        for (int t = 0; t < 6; ++t) {
            const int idx = t * 512 + tid;
            if (idx < STAGE_F4) {
                const int srow = sbase + (idx >> 5);
                const int crow = srow < 0 ? 0 : (srow >= SS ? SS - 1 : srow);
                vals[t] = *(const f4v*)(xb + (size_t)crow * CC + ((idx & 31) << 2));
            }
        }
    };
    auto commit = [&](int c, int buf) {       // regs -> LDS (zero-pad edges)
        const int sbase = q * (CPB * CH) + c * CH - PADW;
        #pragma unroll
        for (int t = 0; t < 6; ++t) {
            const int idx = t * 512 + tid;
            if (idx < STAGE_F4) {
                f4v w = vals[t];
                const int srow = sbase + (idx >> 5);
                if (srow < 0 || srow >= SS) w = (f4v){0.f, 0.f, 0.f, 0.f};
                stage[buf][idx] = w;
            }
        }
    };

    issue(0);
    commit(0, 0);

    for (int c = 0; c < CPB; ++c) {
        __syncthreads();                      // stage[c&1] ready
        const int cur = c & 1;
        if (c + 1 < CPB) issue(c + 1);        // overlap loads with compute

        const int S0 = q * (CPB * CH) + c * CH;
        const int r0 = rg * 8;
        const f2v* stg = (const f2v*)stage[cur];

        f2v win[KW];
        #pragma unroll
        for (int j = 0; j < KW; ++j) win[j] = stg[(r0 + j) * 64 + cp];

        #pragma unroll
        for (int i = 0; i < 8; ++i) {
            // fp32 sequential sum, ascending window order == XLA reduce_window
            float ax = win[0].x, ay = win[0].y;
            #pragma unroll
            for (int j = 1; j < KW; ++j) { ax += win[j].x; ay += win[j].y; }
            f2v tf;
            tf.x = ax / 25.0f;                // IEEE f32 divide, matches sums/K
            tf.y = ay / 25.0f;
            const int row = (S0 + r0 + i) * 64 + cp;
            __builtin_nontemporal_store(tf, &tb[row]);

            const f2v xv = win[PADW];         // x[s]
            f2v so;
            so.x = (cnd.x > 0.5f) ? xv.x / (tf.x + 1e-8f) : xv.x - tf.x;
            so.y = (cnd.y > 0.5f) ? xv.y / (tf.y + 1e-8f) : xv.y - tf.y;
            __builtin_nontemporal_store(so, &sv[row]);

            #pragma unroll
            for (int j = 0; j < KW - 1; ++j) win[j] = win[j + 1];
            if (i < 7) win[KW - 1] = stg[(r0 + i + KW) * 64 + cp];
        }

        if (c + 1 < CPB) commit(c + 1, cur ^ 1);
    }
}

extern "C" void kernel_launch(void* const* d_in, const int* in_sizes, int n_in,
                              void* d_out, int out_size, void* d_ws, size_t ws_size,
                              hipStream_t stream) {
    const float* x = (const float*)d_in[0];
    float* out = (float*)d_out;
    float* trend = out;                               // output 0
    float* seasonal = out + (size_t)BB * SS * CC;     // output 1

    // KA's stats (7*64*4096 floats = 7.3 MiB) live at the start of the
    // seasonal half; K2 consumes them before KB overwrites seasonal.
    float* stats = seasonal;
    float* condf = (float*)d_ws;                      // 4096 floats

    ka_stats<<<dim3(512), dim3(256), 0, stream>>>(x, stats);
    k2_finalize<<<dim3(NSERIES / 32), dim3(256), 0, stream>>>(stats, condf);
    kb_outputs<<<dim3(BB * 8), dim3(512), 0, stream>>>(x, condf, trend, seasonal);
}